// Round 6
// baseline (204.622 us; speedup 1.0000x reference)
//
#include <hip/hip_runtime.h>

typedef __attribute__((ext_vector_type(8))) short bf16x8;
typedef __attribute__((ext_vector_type(4))) float f32x4;
typedef unsigned int u32;
typedef unsigned short u16;
typedef unsigned long long u64;

#define S0 384
#define PLANE0 (384 * 384)
#define NXT 12            // x tiles
#define XROWB 10240       // bytes per (xtile,row) image: 40 px * 16 oct * 16B
#define XTILEB ((size_t)386 * XROWB)

#define GLOAD_LDS(g, l) __builtin_amdgcn_global_load_lds( \
    (const __attribute__((address_space(1))) void*)(g),   \
    (__attribute__((address_space(3))) void*)(l), 16, 0, 0)

__device__ __forceinline__ u16 bfr(float f) {   // f32 -> bf16 RNE
    u32 b = __float_as_uint(f);
    b += 0x7fff + ((b >> 16) & 1);
    return (u16)(b >> 16);
}

// ---------------------------------------------------------------------------
// Stage 1: v[k,m,d] = lin0_b[m] + sum_{r<128} lin0_w[m,r] * feats[3r+k, d]
// ---------------------------------------------------------------------------
__global__ void k_v(const float* __restrict__ V,
                    const float* __restrict__ lin0_w,
                    const float* __restrict__ lin0_b,
                    float* __restrict__ v_out) {
    int blk = blockIdx.x;          // 0..194
    int k = blk / 65, m = blk % 65;
    int d = threadIdx.x;           // 0..255
    int t = d >> 5, f = d & 31;
    const float* vbase = V + (size_t)t * 384 * 33 + f;
    float acc = lin0_b[m];
    for (int r = 0; r < 128; ++r) {
        float w = lin0_w[m * 130 + r];
        acc += w * vbase[(3 * r + k) * 33];
    }
    v_out[(size_t)blk * 256 + d] = acc;
}

// ---------------------------------------------------------------------------
// Stage 2: attention scalars A[k,t] (9 floats)
// ---------------------------------------------------------------------------
__global__ void k_att(const float* __restrict__ v,
                      const float* __restrict__ att_w,
                      const float* __restrict__ att_b,
                      const float* __restrict__ agg,
                      float* __restrict__ A_out) {
    int k = blockIdx.x;
    int tid = threadIdx.x;
    __shared__ float wv1[256], wv2[256];
    __shared__ float sbuf[3][65];
    __shared__ float Ck_s;
    __shared__ float sm[3];
    {
        int d = tid;
        float a1 = 0.f, a2 = 0.f;
        for (int h = 0; h < 64; ++h) {
            float w = att_w[((size_t)(k * 64 + h)) * 256 + d];
            a1 += agg[k * 128 + h] * w;
            a2 += agg[k * 128 + 64 + h] * w;
        }
        wv1[d] = a1;
        wv2[d] = a2;
    }
    if (tid == 0) {
        float c = 0.f;
        for (int h = 0; h < 64; ++h)
            c += (agg[k * 128 + h] + agg[k * 128 + 64 + h]) * att_b[k * 64 + h];
        Ck_s = c;
    }
    __syncthreads();
    if (tid < 195) {
        int t = tid / 65, m = tid % 65;
        const float* vt = v + ((size_t)(t * 65 + m)) * 256;
        const float* vk = v + ((size_t)(k * 65 + m)) * 256;
        float s = Ck_s;
        for (int d = 0; d < 256; ++d)
            s += vt[d] * wv1[d] + vk[d] * wv2[d];
        s = s > 0.f ? s : 0.01f * s;
        sbuf[t][m] = s;
    }
    __syncthreads();
    if (tid < 3) {
        float mx = sbuf[tid][0];
        for (int m = 1; m < 65; ++m) mx = fmaxf(mx, sbuf[tid][m]);
        sm[tid] = mx;
    }
    __syncthreads();
    if (tid == 0) {
        float mx = fmaxf(sm[0], fmaxf(sm[1], sm[2]));
        float e0 = __expf(sm[0] - mx), e1 = __expf(sm[1] - mx), e2 = __expf(sm[2] - mx);
        float inv = 1.f / (e0 + e1 + e2);
        A_out[k * 3 + 0] = e0 * inv;
        A_out[k * 3 + 1] = e1 * inv;
        A_out[k * 3 + 2] = e2 * inv;
    }
}

// ---------------------------------------------------------------------------
// Composed-conv weight prep: E laid out tap-major for the conv's A-frags:
//   Ebf2[(tap*4 + icg)*128 + oc][32]   (icg = ic>>5, elem = ic&31)
// b_eff[o] = cb[o] + sum_m cb[m]*sum(W[o][m][:][:]).
// ---------------------------------------------------------------------------
__global__ void k_prep_E(const float* __restrict__ cw, const float* __restrict__ cb,
                         u16* __restrict__ Ebf2, float* __restrict__ beff) {
    int o = blockIdx.x, i = threadIdx.x;
    __shared__ float4 Wo[128];
    __shared__ float red[128];
    Wo[i] = *(const float4*)(cw + (size_t)(o * 128 + i) * 4);
    __syncthreads();
    float a9[9];
#pragma unroll
    for (int q = 0; q < 9; ++q) a9[q] = 0.f;
    for (int m = 0; m < 128; ++m) {
        float4 w1 = *(const float4*)(cw + (size_t)(m * 128 + i) * 4);  // W[m][i]
        float4 w2 = Wo[m];                                             // W[o][m]
        a9[0] += w2.x * w1.x;
        a9[1] += w2.x * w1.y + w2.y * w1.x;
        a9[2] += w2.y * w1.y;
        a9[3] += w2.x * w1.z + w2.z * w1.x;
        a9[4] += w2.x * w1.w + w2.y * w1.z + w2.z * w1.y + w2.w * w1.x;
        a9[5] += w2.y * w1.w + w2.w * w1.y;
        a9[6] += w2.z * w1.z;
        a9[7] += w2.z * w1.w + w2.w * w1.z;
        a9[8] += w2.w * w1.w;
    }
    int icg = i >> 5, el = i & 31;
#pragma unroll
    for (int q = 0; q < 9; ++q)
        Ebf2[(size_t)((q * 4 + icg) * 128 + o) * 32 + el] = bfr(a9[q]);
    float4 wo = Wo[i];
    red[i] = cb[i] * (wo.x + wo.y + wo.z + wo.w);
    __syncthreads();
    for (int s = 64; s > 0; s >>= 1) {
        if (i < s) red[i] += red[i + s];
        __syncthreads();
    }
    if (i == 0) beff[o] = cb[o] + red[0];
}

// ---------------------------------------------------------------------------
// Pack: Xbf2[xtile][y][unit 0..639] = exact LDS image per (xtile,row):
//   unit = p*16 + j holds 8 bf16 of ic-octet (j ^ (p&15)) at input (y, x0+p),
//   value = graph * att9[y%3][x%3], zero-padded (x>=384 or y>=384).
// grid (12, 193), 256 threads, 5 units each (2 rows of 640).
// ---------------------------------------------------------------------------
__global__ __launch_bounds__(256) void k_pack(
        const float* __restrict__ graph,
        const float* __restrict__ A9g,
        u16* __restrict__ Xbf2) {
    const int xtile = blockIdx.x, yb = blockIdx.y;
    const int tid = threadIdx.x;
    float a9[9];
#pragma unroll
    for (int q = 0; q < 9; ++q) a9[q] = A9g[q];
#pragma unroll
    for (int i = 0; i < 5; ++i) {
        int u = tid + i * 256;            // 0..1279
        int r = (u >= 640) ? 1 : 0;
        int rem = u - r * 640;
        int p = rem >> 4, j = rem & 15;
        int y = yb * 2 + r;
        int x = xtile * 32 + p;
        int oct = j ^ (p & 15);
        uint4 w = {0u, 0u, 0u, 0u};
        if (x < S0 && y < S0) {
            float f = a9[(y % 3) * 3 + (x % 3)];
            const float* g0 = graph + (size_t)(oct * 8) * PLANE0 + (size_t)y * S0 + x;
            u16 q0 = bfr(g0[0 * (size_t)PLANE0] * f);
            u16 q1 = bfr(g0[1 * (size_t)PLANE0] * f);
            u16 q2 = bfr(g0[2 * (size_t)PLANE0] * f);
            u16 q3 = bfr(g0[3 * (size_t)PLANE0] * f);
            u16 q4 = bfr(g0[4 * (size_t)PLANE0] * f);
            u16 q5 = bfr(g0[5 * (size_t)PLANE0] * f);
            u16 q6 = bfr(g0[6 * (size_t)PLANE0] * f);
            u16 q7 = bfr(g0[7 * (size_t)PLANE0] * f);
            w.x = (u32)q0 | ((u32)q1 << 16);
            w.y = (u32)q2 | ((u32)q3 << 16);
            w.z = (u32)q4 | ((u32)q5 << 16);
            w.w = (u32)q6 | ((u32)q7 << 16);
        }
        *(uint4*)((char*)Xbf2 + (size_t)xtile * XTILEB + (size_t)y * XROWB + rem * 16) = w;
    }
}

// ---------------------------------------------------------------------------
// Fused 3x3 conv (composed 2x2∘2x2).  Block: 128 oc x 32 px x 2 rows.
// Staging: 40 KB contiguous global_load_lds (pre-baked image, swizzle incl).
// Wave w = (ocg = w&1 -> 64 oc, rwg = w>>1 -> row).  36 barrier-free k-steps.
// LDS read: byte = ((rw*40 + px)<<8) + (((icg*4+l16) ^ (px&15))<<4).
// Epilogue: out = relu(pl*(acc + beff) + graph).
// grid 2304 (bijective XCD chunk swizzle), 256 threads.
// ---------------------------------------------------------------------------
__global__ __launch_bounds__(256) void k_conv9(
        const u16* __restrict__ Xbf2,
        const short* __restrict__ Ebf2,
        const float* __restrict__ beff,
        const float* __restrict__ pl,
        const float* __restrict__ graph,
        float* __restrict__ out) {
    __shared__ __align__(16) u16 Bt[20480];   // 40960 B
    const int tid = threadIdx.x;
    const int lane = tid & 63, wave = tid >> 6;
    const int l15 = lane & 15, l16 = lane >> 4;

    const int phys = blockIdx.x;                       // 0..2303
    const int logical = (phys & 7) * 288 + (phys >> 3);
    const int bx = logical % NXT, by = logical / NXT;
    const int x0 = bx * 32, y0 = by * 2;
    const int ocg = wave & 1, rwg = wave >> 1;
    const int ocbase = ocg * 64;

    // ---- stage 40 KB: rows y0..y0+3 of tile bx, linear -> linear ----
    {
        const char* gsrc = (const char*)Xbf2 + (size_t)bx * XTILEB
                         + (size_t)y0 * XROWB + (size_t)wave * 1024 + lane * 16;
        char* ldst = (char*)Bt + wave * 1024;
#pragma unroll
        for (int i = 0; i < 10; ++i)
            GLOAD_LDS(gsrc + (size_t)i * 4096, ldst + i * 4096);
    }
    __syncthreads();

    f32x4 acc[4][2];
#pragma unroll
    for (int a = 0; a < 4; ++a)
#pragma unroll
        for (int b = 0; b < 2; ++b)
            acc[a][b] = (f32x4){0.f, 0.f, 0.f, 0.f};

    // ---- 36 k-steps, no barriers ----
#pragma unroll
    for (int tap = 0; tap < 9; ++tap) {
        const int dy = tap / 3, dx = tap % 3;
        const int rw = rwg + dy;
        const int pb = l15 + dx;
        const int sx = pb & 15;
#pragma unroll
        for (int icg = 0; icg < 4; ++icg) {
            const short* Ap = Ebf2 + ((size_t)((tap * 4 + icg) * 128 + ocbase + l15) << 5)
                              + l16 * 8;
            bf16x8 fa0 = *(const bf16x8*)(Ap);
            bf16x8 fa1 = *(const bf16x8*)(Ap + 512);
            bf16x8 fa2 = *(const bf16x8*)(Ap + 1024);
            bf16x8 fa3 = *(const bf16x8*)(Ap + 1536);
            const int sz = ((icg * 4 + l16) ^ sx) << 4;
#pragma unroll
            for (int ni = 0; ni < 2; ++ni) {
                const bf16x8 bv = *(const bf16x8*)((const char*)Bt
                    + ((rw * 40 + ni * 16 + pb) << 8) + sz);
                acc[0][ni] = __builtin_amdgcn_mfma_f32_16x16x32_bf16(fa0, bv, acc[0][ni], 0, 0, 0);
                acc[1][ni] = __builtin_amdgcn_mfma_f32_16x16x32_bf16(fa1, bv, acc[1][ni], 0, 0, 0);
                acc[2][ni] = __builtin_amdgcn_mfma_f32_16x16x32_bf16(fa2, bv, acc[2][ni], 0, 0, 0);
                acc[3][ni] = __builtin_amdgcn_mfma_f32_16x16x32_bf16(fa3, bv, acc[3][ni], 0, 0, 0);
            }
        }
        __builtin_amdgcn_sched_barrier(0);   // bound A-load hoisting pressure
    }

    // ---- epilogue ----
    const float plv = pl[0];
    const int yy = y0 + rwg;
#pragma unroll
    for (int mi = 0; mi < 4; ++mi) {
#pragma unroll
        for (int r4 = 0; r4 < 4; ++r4) {
            const int oc = ocbase + mi * 16 + l16 * 4 + r4;
            const float bias = beff[oc];
            const float* grow = graph + (size_t)oc * PLANE0 + (size_t)yy * S0 + x0;
            float* orow = out + (size_t)oc * PLANE0 + (size_t)yy * S0 + x0;
#pragma unroll
            for (int ni = 0; ni < 2; ++ni) {
                int xx = ni * 16 + l15;
                float v = plv * (acc[mi][ni][r4] + bias) + grow[xx];
                orow[xx] = v > 0.f ? v : 0.f;
            }
        }
    }
}

// ---------------------------------------------------------------------------
extern "C" void kernel_launch(void* const* d_in, const int* in_sizes, int n_in,
                              void* d_out, int out_size, void* d_ws, size_t ws_size,
                              hipStream_t stream) {
    (void)in_sizes; (void)n_in; (void)out_size; (void)ws_size;
    const float* V      = (const float*)d_in[0];
    const float* graph  = (const float*)d_in[1];
    const float* lin0_w = (const float*)d_in[4];
    const float* lin0_b = (const float*)d_in[5];
    const float* att_w  = (const float*)d_in[6];
    const float* att_b  = (const float*)d_in[7];
    const float* agg    = (const float*)d_in[8];
    const float* pl     = (const float*)d_in[9];
    const float* cw     = (const float*)d_in[10];
    const float* cb     = (const float*)d_in[11];
    float* out = (float*)d_out;

    char* ws = (char*)d_ws;
    float* v_ws  = (float*)ws;                      // 3*65*256 f32 (199680 B)
    float* A_ws  = (float*)(ws + 200704);           // 9 f32
    u16*   Ebf2  = (u16*)(ws + 200768);             // 9*4*128*32 bf16 = 294912 B
    float* beff  = (float*)(ws + 495680);           // 128 f32
    u16*   Xbf2  = (u16*)(ws + 496192);             // 12*386*10240 B = 47.4 MB

    k_prep_E<<<128, 128, 0, stream>>>(cw, cb, Ebf2, beff);
    k_v<<<195, 256, 0, stream>>>(V, lin0_w, lin0_b, v_ws);
    k_att<<<3, 256, 0, stream>>>(v_ws, att_w, att_b, agg, A_ws);
    k_pack<<<dim3(NXT, 193), 256, 0, stream>>>(graph, A_ws, Xbf2);
    k_conv9<<<2304, 256, 0, stream>>>(
        Xbf2, (const short*)Ebf2, beff, pl, graph, out);
}

// Round 7
// 179.352 us; speedup vs baseline: 1.1409x; 1.1409x over previous
//
#include <hip/hip_runtime.h>

typedef __attribute__((ext_vector_type(8))) short bf16x8;
typedef __attribute__((ext_vector_type(4))) float f32x4;
typedef unsigned int u32;
typedef unsigned short u16;
typedef unsigned long long u64;

#define S0 384
#define PLANE0 (384 * 384)
#define XR 386                     // packed image dim (386x386 records)
#define XROWB ((size_t)XR * 256)   // 98816 B per packed row

#define GLOAD_LDS(g, l) __builtin_amdgcn_global_load_lds( \
    (const __attribute__((address_space(1))) void*)(g),   \
    (__attribute__((address_space(3))) void*)(l), 16, 0, 0)

__device__ __forceinline__ u16 bfr(float f) {   // f32 -> bf16 RNE
    u32 b = __float_as_uint(f);
    b += 0x7fff + ((b >> 16) & 1);
    return (u16)(b >> 16);
}

// ---------------------------------------------------------------------------
// Stage 1: v[k,m,d] = lin0_b[m] + sum_{r<128} lin0_w[m,r] * feats[3r+k, d]
// ---------------------------------------------------------------------------
__global__ void k_v(const float* __restrict__ V,
                    const float* __restrict__ lin0_w,
                    const float* __restrict__ lin0_b,
                    float* __restrict__ v_out) {
    int blk = blockIdx.x;          // 0..194
    int k = blk / 65, m = blk % 65;
    int d = threadIdx.x;           // 0..255
    int t = d >> 5, f = d & 31;
    const float* vbase = V + (size_t)t * 384 * 33 + f;
    float acc = lin0_b[m];
    for (int r = 0; r < 128; ++r) {
        float w = lin0_w[m * 130 + r];
        acc += w * vbase[(3 * r + k) * 33];
    }
    v_out[(size_t)blk * 256 + d] = acc;
}

// ---------------------------------------------------------------------------
// Stage 2: attention scalars A[k,t] (9 floats)
// ---------------------------------------------------------------------------
__global__ void k_att(const float* __restrict__ v,
                      const float* __restrict__ att_w,
                      const float* __restrict__ att_b,
                      const float* __restrict__ agg,
                      float* __restrict__ A_out) {
    int k = blockIdx.x;
    int tid = threadIdx.x;
    __shared__ float wv1[256], wv2[256];
    __shared__ float sbuf[3][65];
    __shared__ float Ck_s;
    __shared__ float sm[3];
    {
        int d = tid;
        float a1 = 0.f, a2 = 0.f;
        for (int h = 0; h < 64; ++h) {
            float w = att_w[((size_t)(k * 64 + h)) * 256 + d];
            a1 += agg[k * 128 + h] * w;
            a2 += agg[k * 128 + 64 + h] * w;
        }
        wv1[d] = a1;
        wv2[d] = a2;
    }
    if (tid == 0) {
        float c = 0.f;
        for (int h = 0; h < 64; ++h)
            c += (agg[k * 128 + h] + agg[k * 128 + 64 + h]) * att_b[k * 64 + h];
        Ck_s = c;
    }
    __syncthreads();
    if (tid < 195) {
        int t = tid / 65, m = tid % 65;
        const float* vt = v + ((size_t)(t * 65 + m)) * 256;
        const float* vk = v + ((size_t)(k * 65 + m)) * 256;
        float s = Ck_s;
        for (int d = 0; d < 256; ++d)
            s += vt[d] * wv1[d] + vk[d] * wv2[d];
        s = s > 0.f ? s : 0.01f * s;
        sbuf[t][m] = s;
    }
    __syncthreads();
    if (tid < 3) {
        float mx = sbuf[tid][0];
        for (int m = 1; m < 65; ++m) mx = fmaxf(mx, sbuf[tid][m]);
        sm[tid] = mx;
    }
    __syncthreads();
    if (tid == 0) {
        float mx = fmaxf(sm[0], fmaxf(sm[1], sm[2]));
        float e0 = __expf(sm[0] - mx), e1 = __expf(sm[1] - mx), e2 = __expf(sm[2] - mx);
        float inv = 1.f / (e0 + e1 + e2);
        A_out[k * 3 + 0] = e0 * inv;
        A_out[k * 3 + 1] = e1 * inv;
        A_out[k * 3 + 2] = e2 * inv;
    }
}

// ---------------------------------------------------------------------------
// Composed-conv weight prep: Ebf2[(tap*4+icg)*128 + oc][32k] bf16, and
// b_eff[o] = cb[o] + sum_m cb[m]*sum(W[o][m][:][:]).
// ---------------------------------------------------------------------------
__global__ void k_prep_E(const float* __restrict__ cw, const float* __restrict__ cb,
                         u16* __restrict__ Ebf2, float* __restrict__ beff) {
    int o = blockIdx.x, i = threadIdx.x;
    __shared__ float4 Wo[128];
    __shared__ float red[128];
    Wo[i] = *(const float4*)(cw + (size_t)(o * 128 + i) * 4);
    __syncthreads();
    float a9[9];
#pragma unroll
    for (int q = 0; q < 9; ++q) a9[q] = 0.f;
    for (int m = 0; m < 128; ++m) {
        float4 w1 = *(const float4*)(cw + (size_t)(m * 128 + i) * 4);  // W[m][i]
        float4 w2 = Wo[m];                                             // W[o][m]
        a9[0] += w2.x * w1.x;
        a9[1] += w2.x * w1.y + w2.y * w1.x;
        a9[2] += w2.y * w1.y;
        a9[3] += w2.x * w1.z + w2.z * w1.x;
        a9[4] += w2.x * w1.w + w2.y * w1.z + w2.z * w1.y + w2.w * w1.x;
        a9[5] += w2.y * w1.w + w2.w * w1.y;
        a9[6] += w2.z * w1.z;
        a9[7] += w2.z * w1.w + w2.w * w1.z;
        a9[8] += w2.w * w1.w;
    }
    int icg = i >> 5, el = i & 31;
#pragma unroll
    for (int q = 0; q < 9; ++q)
        Ebf2[(size_t)((q * 4 + icg) * 128 + o) * 32 + el] = bfr(a9[q]);
    float4 wo = Wo[i];
    red[i] = cb[i] * (wo.x + wo.y + wo.z + wo.w);
    __syncthreads();
    for (int s = 64; s > 0; s >>= 1) {
        if (i < s) red[i] += red[i + s];
        __syncthreads();
    }
    if (i == 0) beff[o] = cb[o] + red[0];
}

// ---------------------------------------------------------------------------
// Zero-fill packed image border: rows 384-385 (contiguous tail) and
// cols 384-385 of rows 0..383.  24640 uint4 units.
// ---------------------------------------------------------------------------
__global__ void k_zero(uint4* __restrict__ X4) {
    int idx = blockIdx.x * 256 + threadIdx.x;
    const uint4 z = {0u, 0u, 0u, 0u};
    if (idx < 12352) {                       // rows 384,385: records 148224..148995
        X4[(size_t)148224 * 16 + idx] = z;
    } else if (idx < 24640) {
        int k = idx - 12352;                 // 12288 units
        int y = k >> 5, r = k & 31;
        int x = 384 + (r >> 4), j = r & 15;
        X4[((size_t)y * XR + x) * 16 + j] = z;
    }
}

// ---------------------------------------------------------------------------
// Pack (coalesced transpose): X[y][x][slot j 16B] where slot j holds
// ic-octet (j ^ (x&15)) of graph[.][y][x] * att9[y%3][x%3], bf16.
// Block = (xtile of 128 x, one y).  LDS transpose buffer [128x][136] u16.
// grid (3, 384), 256 threads.
// ---------------------------------------------------------------------------
__global__ __launch_bounds__(256) void k_pack(
        const float* __restrict__ graph,
        const float* __restrict__ A9g,
        u16* __restrict__ X) {
    __shared__ u16 T[128 * 136];
    const int tid = threadIdx.x;
    const int xt = blockIdx.x, y = blockIdx.y;
    const int x0p = xt * 128;

    // phase A: read 4 ic x 16 x, transpose into LDS
    const int ic0 = (tid & 31) * 4;
    const int xc = tid >> 5;                 // 0..7
    float ar[3];
    ar[0] = A9g[(y % 3) * 3 + 0];
    ar[1] = A9g[(y % 3) * 3 + 1];
    ar[2] = A9g[(y % 3) * 3 + 2];
    const int m0 = (x0p + xc * 16) % 3;
    float facs[3];
    facs[0] = ar[m0];
    facs[1] = ar[m0 + 1 == 3 ? 0 : m0 + 1];
    facs[2] = ar[m0 + 2 >= 3 ? m0 - 1 : m0 + 2];

    float vals[4][16];
#pragma unroll
    for (int ici = 0; ici < 4; ++ici) {
        const float* g = graph + (size_t)(ic0 + ici) * PLANE0 + (size_t)y * S0 + x0p + xc * 16;
#pragma unroll
        for (int q = 0; q < 4; ++q) {
            float4 f = *(const float4*)(g + q * 4);
            vals[ici][q * 4 + 0] = f.x;
            vals[ici][q * 4 + 1] = f.y;
            vals[ici][q * 4 + 2] = f.z;
            vals[ici][q * 4 + 3] = f.w;
        }
    }
#pragma unroll
    for (int e = 0; e < 16; ++e) {
        float f = facs[e % 3];
        int x = xc * 16 + e;
        u16 q0 = bfr(vals[0][e] * f);
        u16 q1 = bfr(vals[1][e] * f);
        u16 q2 = bfr(vals[2][e] * f);
        u16 q3 = bfr(vals[3][e] * f);
        u64 w = (u64)q0 | ((u64)q1 << 16) | ((u64)q2 << 32) | ((u64)q3 << 48);
        *(u64*)(T + x * 136 + ic0) = w;
    }
    __syncthreads();

    // phase B: apply swizzle, write coalesced 16B units
#pragma unroll
    for (int i = 0; i < 8; ++i) {
        int u = tid + 256 * i;               // 0..2047
        int x = u >> 4, j = u & 15;
        int oct = j ^ (x & 15);
        uint4 w = *(const uint4*)(T + x * 136 + oct * 8);
        *(uint4*)((char*)X + ((size_t)y * XR + x0p + x) * 256 + j * 16) = w;
    }
}

// ---------------------------------------------------------------------------
// Fused 3x3 conv (composed 2x2∘2x2), GEMM M=128oc K=1152 on packed X.
// Block: 128oc x 32px x 4rows (N=128).  4 waves = 2 M-halves x 2 row-bands;
// wave = 64oc x 32px x 2rows.  Stage 6 rows x 34px x 256B = 52224B LDS once
// (global_load_lds, linear), 1 barrier, then 36 barrier-free k-steps with
// one-step-ahead A prefetch.  Epilogue: out = relu(pl*(acc+beff) + graph).
// grid 1152 (8x144 XCD chunk swizzle), 256 threads.
// ---------------------------------------------------------------------------
__global__ __launch_bounds__(256) void k_conv9(
        const u16* __restrict__ X,
        const short* __restrict__ Ebf2,
        const float* __restrict__ beff,
        const float* __restrict__ pl,
        const float* __restrict__ graph,
        float* __restrict__ out) {
    __shared__ __align__(16) char Bt[52224];    // 6 rows x 544 x 16B
    const int tid = threadIdx.x;
    const int lane = tid & 63, wave = tid >> 6;
    const int l15 = lane & 15, l16 = lane >> 4;

    const int phys = blockIdx.x;                // 0..1151 = 8 x 144
    const int logical = (phys & 7) * 144 + (phys >> 3);
    const int by = logical / 12, bx = logical % 12;
    const int y0 = by * 4, x0 = bx * 32;
    const int mh = wave & 1, nb = wave >> 1;    // M-half, row-band
    const int ocbase = mh * 64;

    // ---- stage 6 packed rows, linear global -> linear LDS ----
    {
        const char* gsrc = (const char*)X + ((size_t)y0 * XR + x0) * 256;
#pragma unroll
        for (int r = 0; r < 6; ++r) {
            const char* rs = gsrc + (size_t)r * XROWB;
            char* ld = Bt + r * 8704;
            GLOAD_LDS(rs + (size_t)tid * 16, ld + tid * 16);
            GLOAD_LDS(rs + (size_t)(tid + 256) * 16, ld + (tid + 256) * 16);
            if (tid < 32)
                GLOAD_LDS(rs + (size_t)(tid + 512) * 16, ld + (tid + 512) * 16);
        }
    }
    __syncthreads();

    f32x4 acc[4][2][2];    // [m][nr][nx]
#pragma unroll
    for (int a = 0; a < 4; ++a)
#pragma unroll
        for (int b = 0; b < 2; ++b)
#pragma unroll
            for (int c = 0; c < 2; ++c)
                acc[a][b][c] = (f32x4){0.f, 0.f, 0.f, 0.f};

    // ---- 36 k-steps, no barriers, A prefetched one step ahead ----
#define ALOAD(dst, s) {                                                        \
        const short* Ap = Ebf2 + ((size_t)((s) * 128 + ocbase + l15) << 5)     \
                          + l16 * 8;                                           \
        dst[0] = *(const bf16x8*)(Ap);                                         \
        dst[1] = *(const bf16x8*)(Ap + 512);                                   \
        dst[2] = *(const bf16x8*)(Ap + 1024);                                  \
        dst[3] = *(const bf16x8*)(Ap + 1536); }

    bf16x8 fa[4], fn[4];
    ALOAD(fa, 0);
#pragma unroll
    for (int s = 0; s < 36; ++s) {
        if (s < 35) ALOAD(fn, s + 1);
        const int tap = s >> 2, icg = s & 3;
        const int dy = tap / 3, dx = tap % 3;
#pragma unroll
        for (int nr = 0; nr < 2; ++nr) {
            const int row = nb * 2 + nr + dy;
#pragma unroll
            for (int nx = 0; nx < 2; ++nx) {
                const int px = l15 + nx * 16 + dx;
                const int slot = (icg * 4 + l16) ^ (px & 15);
                const bf16x8 bv = *(const bf16x8*)(Bt
                    + ((row * 34 + px) << 8) + (slot << 4));
                acc[0][nr][nx] = __builtin_amdgcn_mfma_f32_16x16x32_bf16(fa[0], bv, acc[0][nr][nx], 0, 0, 0);
                acc[1][nr][nx] = __builtin_amdgcn_mfma_f32_16x16x32_bf16(fa[1], bv, acc[1][nr][nx], 0, 0, 0);
                acc[2][nr][nx] = __builtin_amdgcn_mfma_f32_16x16x32_bf16(fa[2], bv, acc[2][nr][nx], 0, 0, 0);
                acc[3][nr][nx] = __builtin_amdgcn_mfma_f32_16x16x32_bf16(fa[3], bv, acc[3][nr][nx], 0, 0, 0);
            }
        }
#pragma unroll
        for (int m = 0; m < 4; ++m) fa[m] = fn[m];
    }
#undef ALOAD

    // ---- epilogue: out = relu(pl*(acc + beff) + graph) ----
    const float plv = pl[0];
#pragma unroll
    for (int nr = 0; nr < 2; ++nr) {
        const int yy = y0 + nb * 2 + nr;
#pragma unroll
        for (int m = 0; m < 4; ++m) {
#pragma unroll
            for (int r4 = 0; r4 < 4; ++r4) {
                const int oc = ocbase + m * 16 + l16 * 4 + r4;
                const float bias = beff[oc];
                const float* grow = graph + (size_t)oc * PLANE0 + (size_t)yy * S0 + x0;
                float* orow = out + (size_t)oc * PLANE0 + (size_t)yy * S0 + x0;
#pragma unroll
                for (int nx = 0; nx < 2; ++nx) {
                    const int xx = nx * 16 + l15;
                    float v = plv * (acc[m][nr][nx][r4] + bias) + grow[xx];
                    orow[xx] = v > 0.f ? v : 0.f;
                }
            }
        }
    }
}

// ---------------------------------------------------------------------------
extern "C" void kernel_launch(void* const* d_in, const int* in_sizes, int n_in,
                              void* d_out, int out_size, void* d_ws, size_t ws_size,
                              hipStream_t stream) {
    (void)in_sizes; (void)n_in; (void)out_size; (void)ws_size;
    const float* V      = (const float*)d_in[0];
    const float* graph  = (const float*)d_in[1];
    const float* lin0_w = (const float*)d_in[4];
    const float* lin0_b = (const float*)d_in[5];
    const float* att_w  = (const float*)d_in[6];
    const float* att_b  = (const float*)d_in[7];
    const float* agg    = (const float*)d_in[8];
    const float* pl     = (const float*)d_in[9];
    const float* cw     = (const float*)d_in[10];
    const float* cb     = (const float*)d_in[11];
    float* out = (float*)d_out;

    char* ws = (char*)d_ws;
    float* v_ws  = (float*)ws;                      // 3*65*256 f32 (199680 B)
    float* A_ws  = (float*)(ws + 200704);           // 9 f32
    u16*   Ebf2  = (u16*)(ws + 200768);             // 294912 B
    float* beff  = (float*)(ws + 495680);           // 128 f32
    u16*   X     = (u16*)(ws + 496192);             // 386*386*256 B = 38.1 MB

    k_prep_E<<<128, 128, 0, stream>>>(cw, cb, Ebf2, beff);
    k_v<<<195, 256, 0, stream>>>(V, lin0_w, lin0_b, v_ws);
    k_att<<<3, 256, 0, stream>>>(v_ws, att_w, att_b, agg, A_ws);
    k_zero<<<97, 256, 0, stream>>>((uint4*)X);
    k_pack<<<dim3(3, 384), 256, 0, stream>>>(graph, A_ws, X);
    k_conv9<<<1152, 256, 0, stream>>>(
        X, (const short*)Ebf2, beff, pl, graph, out);
}

// Round 8
// 140.856 us; speedup vs baseline: 1.4527x; 1.2733x over previous
//
#include <hip/hip_runtime.h>

typedef __attribute__((ext_vector_type(8))) short bf16x8;
typedef __attribute__((ext_vector_type(4))) float f32x4;
typedef unsigned int u32;
typedef unsigned short u16;
typedef unsigned long long u64;

#define S0 384
#define PLANE0 (384 * 384)
#define XR 386                     // packed image dim (386x386 records)
#define XROWB ((size_t)XR * 256)   // 98816 B per packed row

#define GLOAD_LDS(g, l) __builtin_amdgcn_global_load_lds( \
    (const __attribute__((address_space(1))) void*)(g),   \
    (__attribute__((address_space(3))) void*)(l), 16, 0, 0)

__device__ __forceinline__ u16 bfr(float f) {   // f32 -> bf16 RNE
    u32 b = __float_as_uint(f);
    b += 0x7fff + ((b >> 16) & 1);
    return (u16)(b >> 16);
}

// ---------------------------------------------------------------------------
// Stage 1: v[k,m,d] = lin0_b[m] + sum_{r<128} lin0_w[m,r] * feats[3r+k, d]
// ---------------------------------------------------------------------------
__global__ void k_v(const float* __restrict__ V,
                    const float* __restrict__ lin0_w,
                    const float* __restrict__ lin0_b,
                    float* __restrict__ v_out) {
    int blk = blockIdx.x;          // 0..194
    int k = blk / 65, m = blk % 65;
    int d = threadIdx.x;           // 0..255
    int t = d >> 5, f = d & 31;
    const float* vbase = V + (size_t)t * 384 * 33 + f;
    float acc = lin0_b[m];
    for (int r = 0; r < 128; ++r) {
        float w = lin0_w[m * 130 + r];
        acc += w * vbase[(3 * r + k) * 33];
    }
    v_out[(size_t)blk * 256 + d] = acc;
}

// ---------------------------------------------------------------------------
// Stage 2: attention scalars A[k,t] (9 floats)
// ---------------------------------------------------------------------------
__global__ void k_att(const float* __restrict__ v,
                      const float* __restrict__ att_w,
                      const float* __restrict__ att_b,
                      const float* __restrict__ agg,
                      float* __restrict__ A_out) {
    int k = blockIdx.x;
    int tid = threadIdx.x;
    __shared__ float wv1[256], wv2[256];
    __shared__ float sbuf[3][65];
    __shared__ float Ck_s;
    __shared__ float sm[3];
    {
        int d = tid;
        float a1 = 0.f, a2 = 0.f;
        for (int h = 0; h < 64; ++h) {
            float w = att_w[((size_t)(k * 64 + h)) * 256 + d];
            a1 += agg[k * 128 + h] * w;
            a2 += agg[k * 128 + 64 + h] * w;
        }
        wv1[d] = a1;
        wv2[d] = a2;
    }
    if (tid == 0) {
        float c = 0.f;
        for (int h = 0; h < 64; ++h)
            c += (agg[k * 128 + h] + agg[k * 128 + 64 + h]) * att_b[k * 64 + h];
        Ck_s = c;
    }
    __syncthreads();
    if (tid < 195) {
        int t = tid / 65, m = tid % 65;
        const float* vt = v + ((size_t)(t * 65 + m)) * 256;
        const float* vk = v + ((size_t)(k * 65 + m)) * 256;
        float s = Ck_s;
        for (int d = 0; d < 256; ++d)
            s += vt[d] * wv1[d] + vk[d] * wv2[d];
        s = s > 0.f ? s : 0.01f * s;
        sbuf[t][m] = s;
    }
    __syncthreads();
    if (tid < 3) {
        float mx = sbuf[tid][0];
        for (int m = 1; m < 65; ++m) mx = fmaxf(mx, sbuf[tid][m]);
        sm[tid] = mx;
    }
    __syncthreads();
    if (tid == 0) {
        float mx = fmaxf(sm[0], fmaxf(sm[1], sm[2]));
        float e0 = __expf(sm[0] - mx), e1 = __expf(sm[1] - mx), e2 = __expf(sm[2] - mx);
        float inv = 1.f / (e0 + e1 + e2);
        A_out[k * 3 + 0] = e0 * inv;
        A_out[k * 3 + 1] = e1 * inv;
        A_out[k * 3 + 2] = e2 * inv;
    }
}

// ---------------------------------------------------------------------------
// Composed-conv weight prep: Ebf2[(tap*4+icg)*128 + oc][32k] bf16, and
// b_eff[o] = cb[o] + sum_m cb[m]*sum(W[o][m][:][:]).
// ---------------------------------------------------------------------------
__global__ void k_prep_E(const float* __restrict__ cw, const float* __restrict__ cb,
                         u16* __restrict__ Ebf2, float* __restrict__ beff) {
    int o = blockIdx.x, i = threadIdx.x;
    __shared__ float4 Wo[128];
    __shared__ float red[128];
    Wo[i] = *(const float4*)(cw + (size_t)(o * 128 + i) * 4);
    __syncthreads();
    float a9[9];
#pragma unroll
    for (int q = 0; q < 9; ++q) a9[q] = 0.f;
    for (int m = 0; m < 128; ++m) {
        float4 w1 = *(const float4*)(cw + (size_t)(m * 128 + i) * 4);  // W[m][i]
        float4 w2 = Wo[m];                                             // W[o][m]
        a9[0] += w2.x * w1.x;
        a9[1] += w2.x * w1.y + w2.y * w1.x;
        a9[2] += w2.y * w1.y;
        a9[3] += w2.x * w1.z + w2.z * w1.x;
        a9[4] += w2.x * w1.w + w2.y * w1.z + w2.z * w1.y + w2.w * w1.x;
        a9[5] += w2.y * w1.w + w2.w * w1.y;
        a9[6] += w2.z * w1.z;
        a9[7] += w2.z * w1.w + w2.w * w1.z;
        a9[8] += w2.w * w1.w;
    }
    int icg = i >> 5, el = i & 31;
#pragma unroll
    for (int q = 0; q < 9; ++q)
        Ebf2[(size_t)((q * 4 + icg) * 128 + o) * 32 + el] = bfr(a9[q]);
    float4 wo = Wo[i];
    red[i] = cb[i] * (wo.x + wo.y + wo.z + wo.w);
    __syncthreads();
    for (int s = 64; s > 0; s >>= 1) {
        if (i < s) red[i] += red[i + s];
        __syncthreads();
    }
    if (i == 0) beff[o] = cb[o] + red[0];
}

// ---------------------------------------------------------------------------
// Pack (coalesced transpose) + border zeroing fused.
// X[y][x][slot j 16B]: slot j holds ic-octet (j ^ (x&15)) of
// graph[.][y][x] * att9[y%3][x%3], bf16; zero outside 384x384.
// grid (3, 386), 256 threads.
// ---------------------------------------------------------------------------
__global__ __launch_bounds__(256) void k_pack(
        const float* __restrict__ graph,
        const float* __restrict__ A9g,
        u16* __restrict__ X) {
    __shared__ u16 T[128 * 136];
    const int tid = threadIdx.x;
    const int xt = blockIdx.x, y = blockIdx.y;
    const int x0p = xt * 128;
    const uint4 z = {0u, 0u, 0u, 0u};

    if (y >= 384) {   // rows 384,385: all-zero
        int nunits = (xt == 2) ? 130 * 16 : 128 * 16;
        for (int u = tid; u < nunits; u += 256) {
            int x = x0p + (u >> 4), j = u & 15;
            *(uint4*)((char*)X + ((size_t)y * XR + x) * 256 + j * 16) = z;
        }
        return;
    }

    // phase A: read 4 ic x 16 x, transpose into LDS
    const int ic0 = (tid & 31) * 4;
    const int xc = tid >> 5;                 // 0..7
    float ar[3];
    ar[0] = A9g[(y % 3) * 3 + 0];
    ar[1] = A9g[(y % 3) * 3 + 1];
    ar[2] = A9g[(y % 3) * 3 + 2];
    const int m0 = (x0p + xc * 16) % 3;
    float facs[3];
    facs[0] = ar[m0];
    facs[1] = ar[m0 + 1 == 3 ? 0 : m0 + 1];
    facs[2] = ar[m0 + 2 >= 3 ? m0 - 1 : m0 + 2];

    float vals[4][16];
#pragma unroll
    for (int ici = 0; ici < 4; ++ici) {
        const float* g = graph + (size_t)(ic0 + ici) * PLANE0 + (size_t)y * S0 + x0p + xc * 16;
#pragma unroll
        for (int q = 0; q < 4; ++q) {
            float4 f = *(const float4*)(g + q * 4);
            vals[ici][q * 4 + 0] = f.x;
            vals[ici][q * 4 + 1] = f.y;
            vals[ici][q * 4 + 2] = f.z;
            vals[ici][q * 4 + 3] = f.w;
        }
    }
#pragma unroll
    for (int e = 0; e < 16; ++e) {
        float f = facs[e % 3];
        int x = xc * 16 + e;
        u16 q0 = bfr(vals[0][e] * f);
        u16 q1 = bfr(vals[1][e] * f);
        u16 q2 = bfr(vals[2][e] * f);
        u16 q3 = bfr(vals[3][e] * f);
        u64 w = (u64)q0 | ((u64)q1 << 16) | ((u64)q2 << 32) | ((u64)q3 << 48);
        *(u64*)(T + x * 136 + ic0) = w;
    }
    __syncthreads();

    // phase B: apply swizzle, write coalesced 16B units
#pragma unroll
    for (int i = 0; i < 8; ++i) {
        int u = tid + 256 * i;               // 0..2047
        int x = u >> 4, j = u & 15;
        int oct = j ^ (x & 15);
        uint4 w = *(const uint4*)(T + x * 136 + oct * 8);
        *(uint4*)((char*)X + ((size_t)y * XR + x0p + x) * 256 + j * 16) = w;
    }
    // cols 384,385 zero (only xt==2 borders them)
    if (xt == 2 && tid < 32) {
        int x = 384 + (tid >> 4), j = tid & 15;
        *(uint4*)((char*)X + ((size_t)y * XR + x) * 256 + j * 16) = z;
    }
}

// ---------------------------------------------------------------------------
// Fused 3x3 conv (composed 2x2∘2x2), GEMM M=128oc K=1152 N=147456px.
// Block: 128oc x 64px x 2rows (N=128).  Waves: mh=wave&1 (oc half),
// rh=wave>>1 (row).  Wave tile: 64oc x 64px x 1row.
// LDS: 4 rows x 66 px x 256 B = 67584 B, staged once via global_load_lds.
// 36 barrier-free k-steps; A-regs pipelined depth 4 (covers L2/L3 latency),
// B ds_reads pipelined depth 2.  Epilogue: out = relu(pl*(acc+beff)+graph).
// grid 1152 = 8 XCD x 144 (chunked swizzle), 256 threads, 2 blocks/CU.
// ---------------------------------------------------------------------------
__global__ __launch_bounds__(256, 2) void k_conv9(
        const u16* __restrict__ X,
        const short* __restrict__ Ebf2,
        const float* __restrict__ beff,
        const float* __restrict__ pl,
        const float* __restrict__ graph,
        float* __restrict__ out) {
    __shared__ __align__(16) char Bt[67584];    // 4 rows x 66 px x 256 B
    const int tid = threadIdx.x;
    const int lane = tid & 63, wave = tid >> 6;
    const int l15 = lane & 15, l16 = lane >> 4;

    const int phys = blockIdx.x;                // 0..1151 = 8 x 144
    const int logical = (phys & 7) * 144 + (phys >> 3);
    const int bx = logical % 6, by = logical / 6;
    const int x0 = bx * 64, y0 = by * 2;
    const int mh = wave & 1, rh = wave >> 1;
    const int ocbase = mh * 64;

    // ---- stage 4 packed rows (16896 B each), linear -> linear ----
    {
        const char* gsrc = (const char*)X + ((size_t)y0 * XR + x0) * 256;
#pragma unroll
        for (int r = 0; r < 4; ++r) {
            const char* rs = gsrc + (size_t)r * XROWB;
            char* ld = Bt + r * 16896;
#pragma unroll
            for (int i = 0; i < 4; ++i)
                GLOAD_LDS(rs + (size_t)tid * 16 + i * 4096, ld + tid * 16 + i * 4096);
            if (tid < 32)
                GLOAD_LDS(rs + (size_t)tid * 16 + 16384, ld + tid * 16 + 16384);
        }
    }

    // ---- A-register pipeline, depth 4 ----
#define ALOAD(dst, s) {                                                        \
        const short* Ap = Ebf2 + ((size_t)((s) * 128 + ocbase + l15) << 5)     \
                          + l16 * 8;                                           \
        dst[0] = *(const bf16x8*)(Ap);                                         \
        dst[1] = *(const bf16x8*)(Ap + 512);                                   \
        dst[2] = *(const bf16x8*)(Ap + 1024);                                  \
        dst[3] = *(const bf16x8*)(Ap + 1536); }

    bf16x8 ap[4][4];
    ALOAD(ap[0], 0); ALOAD(ap[1], 1); ALOAD(ap[2], 2); ALOAD(ap[3], 3);

    __syncthreads();

    f32x4 acc[4][4];    // [m][n]
#pragma unroll
    for (int a = 0; a < 4; ++a)
#pragma unroll
        for (int b = 0; b < 4; ++b)
            acc[a][b] = (f32x4){0.f, 0.f, 0.f, 0.f};

    // B LDS address for k-step s, N-frag n (s compile-time constant)
#define BADDR(s, n) (Bt + (rh + ((s) >> 2) / 3) * 16896                        \
        + ((l15 + (n) * 16 + ((s) >> 2) % 3) << 8)                             \
        + (((((s) & 3) * 4 + l16) ^ ((l15 + (n) * 16 + ((s) >> 2) % 3) & 15)) << 4))

    bf16x8 bp[2][4];
#pragma unroll
    for (int n = 0; n < 4; ++n) bp[0][n] = *(const bf16x8*)BADDR(0, n);

#pragma unroll
    for (int s = 0; s < 36; ++s) {
        const int cur = s & 1;
        // prefetch next step's B frags (ds latency hides under MFMAs)
        if (s < 35) {
#pragma unroll
            for (int n = 0; n < 4; ++n)
                bp[cur ^ 1][n] = *(const bf16x8*)BADDR(s + 1, n);
        }
        __builtin_amdgcn_s_setprio(1);
#pragma unroll
        for (int n = 0; n < 4; ++n) {
            acc[0][n] = __builtin_amdgcn_mfma_f32_16x16x32_bf16(ap[s & 3][0], bp[cur][n], acc[0][n], 0, 0, 0);
            acc[1][n] = __builtin_amdgcn_mfma_f32_16x16x32_bf16(ap[s & 3][1], bp[cur][n], acc[1][n], 0, 0, 0);
            acc[2][n] = __builtin_amdgcn_mfma_f32_16x16x32_bf16(ap[s & 3][2], bp[cur][n], acc[2][n], 0, 0, 0);
            acc[3][n] = __builtin_amdgcn_mfma_f32_16x16x32_bf16(ap[s & 3][3], bp[cur][n], acc[3][n], 0, 0, 0);
        }
        __builtin_amdgcn_s_setprio(0);
        // refill A slot 4 steps ahead
        if (s + 4 < 36) ALOAD(ap[s & 3], s + 4);
    }
#undef ALOAD
#undef BADDR

    // ---- epilogue: out = relu(pl*(acc + beff) + graph) ----
    const float plv = pl[0];
    const int yy = y0 + rh;
#pragma unroll
    for (int m = 0; m < 4; ++m) {
#pragma unroll
        for (int r4 = 0; r4 < 4; ++r4) {
            const int oc = ocbase + m * 16 + l16 * 4 + r4;
            const float bias = beff[oc];
            const float* grow = graph + (size_t)oc * PLANE0 + (size_t)yy * S0 + x0;
            float* orow = out + (size_t)oc * PLANE0 + (size_t)yy * S0 + x0;
#pragma unroll
            for (int n = 0; n < 4; ++n) {
                const int xx = n * 16 + l15;
                float v = plv * (acc[m][n][r4] + bias) + grow[xx];
                orow[xx] = v > 0.f ? v : 0.f;
            }
        }
    }
}

// ---------------------------------------------------------------------------
extern "C" void kernel_launch(void* const* d_in, const int* in_sizes, int n_in,
                              void* d_out, int out_size, void* d_ws, size_t ws_size,
                              hipStream_t stream) {
    (void)in_sizes; (void)n_in; (void)out_size; (void)ws_size;
    const float* V      = (const float*)d_in[0];
    const float* graph  = (const float*)d_in[1];
    const float* lin0_w = (const float*)d_in[4];
    const float* lin0_b = (const float*)d_in[5];
    const float* att_w  = (const float*)d_in[6];
    const float* att_b  = (const float*)d_in[7];
    const float* agg    = (const float*)d_in[8];
    const float* pl     = (const float*)d_in[9];
    const float* cw     = (const float*)d_in[10];
    const float* cb     = (const float*)d_in[11];
    float* out = (float*)d_out;

    char* ws = (char*)d_ws;
    float* v_ws  = (float*)ws;                      // 3*65*256 f32 (199680 B)
    float* A_ws  = (float*)(ws + 200704);           // 9 f32
    u16*   Ebf2  = (u16*)(ws + 200768);             // 294912 B
    float* beff  = (float*)(ws + 495680);           // 128 f32
    u16*   X     = (u16*)(ws + 496192);             // 386*386*256 B = 38.1 MB

    k_prep_E<<<128, 128, 0, stream>>>(cw, cb, Ebf2, beff);
    k_v<<<195, 256, 0, stream>>>(V, lin0_w, lin0_b, v_ws);
    k_att<<<3, 256, 0, stream>>>(v_ws, att_w, att_b, agg, A_ws);
    k_pack<<<dim3(3, 386), 256, 0, stream>>>(graph, A_ws, X);
    k_conv9<<<1152, 256, 0, stream>>>(
        X, (const short*)Ebf2, beff, pl, graph, out);
}